// Round 1
// 161.312 us; speedup vs baseline: 1.0396x; 1.0396x over previous
//
#include <hip/hip_runtime.h>
#include <hip/hip_bf16.h>

typedef __bf16 bf16x8 __attribute__((ext_vector_type(8)));
typedef __bf16 bf16x4 __attribute__((ext_vector_type(4)));
typedef float  f32x4  __attribute__((ext_vector_type(4)));

#define T_SEQ 2048
#define D_HEAD 64
#define BH_N 32
#define NT_TILES (T_SEQ / 64)        // 32
#define IMG_BYTES 16384              // per-(bh,kt) tile image: 8KB K + 8KB V
#define SCALE_LOG2 0.18033688011112042f   // 0.125 * log2(e)

#define WS_IMG ((size_t)0)
#define WS_MB  ((size_t)16u << 20)

static __device__ __forceinline__ f32x4 mfma32(bf16x8 a, bf16x8 b, f32x4 c) {
    return __builtin_amdgcn_mfma_f32_16x16x32_bf16(a, b, c, 0, 0, 0);
}

static __device__ __forceinline__ float fast_exp2(float x) {
#if __has_builtin(__builtin_amdgcn_exp2f)
    return __builtin_amdgcn_exp2f(x);   // raw v_exp_f32; inputs bounded, no fixup needed
#else
    return exp2f(x);
#endif
}

// async global->LDS, 16B per lane. LDS dest is wave-uniform base + lane*16 (HW rule);
// the swizzle lives in the GLOBAL image layout, LDS stays linear.
static __device__ __forceinline__ void gload16(const void* g, void* l, int lane) {
#if __has_builtin(__builtin_amdgcn_global_load_lds)
    (void)lane;
    __builtin_amdgcn_global_load_lds(
        (const __attribute__((address_space(1))) void*)g,
        (__attribute__((address_space(3))) void*)l, 16, 0, 0);
#else
    *((f32x4*)l + lane) = *(const f32x4*)g;
#endif
}

// ---------------- prepass: build per-tile LDS images ----------------
// Image for (bh,kt), 16KB:
//   K half (8KB): row kr (key 0..63) x 128B; 16B chunk m = K[key][d-chunk m^(kr&7)]
//   V half (8KB): row r  (d   0..63) x 128B; 16B chunk m: u=m^(r&7), kh=u&1, g=u>>1,
//       bytes0-7 = V[32kh+4g+{0..3}][d=r], bytes8-15 = V[32kh+16+4g+{0..3}][d=r]
// This is byte-identical to what attn8 used to assemble in LDS per iteration.

__global__ __launch_bounds__(256) void prep_kv(const float* __restrict__ k,
                                               const float* __restrict__ v,
                                               char* __restrict__ img) {
    __shared__ __bf16 t[64][72];
    const int bh = blockIdx.y, tt = blockIdx.x, tid = threadIdx.x;
    char* ob = img + ((size_t)bh * NT_TILES + tt) * IMG_BYTES;
    {
        const int kr = tid >> 2, qd = tid & 3, ke = kr & 7;
        const size_t base = ((size_t)bh * T_SEQ + tt * 64 + kr) * D_HEAD + qd * 16;
        const float4 a0 = *(const float4*)(k + base);
        const float4 a1 = *(const float4*)(k + base + 4);
        const float4 a2 = *(const float4*)(k + base + 8);
        const float4 a3 = *(const float4*)(k + base + 12);
        bf16x8 w0, w1;
        w0[0]=(__bf16)a0.x; w0[1]=(__bf16)a0.y; w0[2]=(__bf16)a0.z; w0[3]=(__bf16)a0.w;
        w0[4]=(__bf16)a1.x; w0[5]=(__bf16)a1.y; w0[6]=(__bf16)a1.z; w0[7]=(__bf16)a1.w;
        w1[0]=(__bf16)a2.x; w1[1]=(__bf16)a2.y; w1[2]=(__bf16)a2.z; w1[3]=(__bf16)a2.w;
        w1[4]=(__bf16)a3.x; w1[5]=(__bf16)a3.y; w1[6]=(__bf16)a3.z; w1[7]=(__bf16)a3.w;
        *(bf16x8*)(ob + kr * 128 + (((2 * qd + 0) ^ ke) << 4)) = w0;
        *(bf16x8*)(ob + kr * 128 + (((2 * qd + 1) ^ ke) << 4)) = w1;
    }
    {
        const int tr = tid >> 4, c4 = (tid & 15) * 4;
        const float* src = v + ((size_t)bh * T_SEQ + tt * 64) * D_HEAD;
#pragma unroll
        for (int p = 0; p < 4; ++p) {
            const int row = p * 16 + tr;
            const float4 f = *(const float4*)(src + row * D_HEAD + c4);
            t[c4+0][row] = (__bf16)f.x; t[c4+1][row] = (__bf16)f.y;
            t[c4+2][row] = (__bf16)f.z; t[c4+3][row] = (__bf16)f.w;
        }
        __syncthreads();
        const int d = tid >> 2;
        char* vb = ob + 8192 + d * 128;
#pragma unroll
        for (int mi = 0; mi < 2; ++mi) {
            const int m  = (tid & 3) * 2 + mi;
            const int u  = m ^ (d & 7);
            const int k0 = (u & 1) * 32 + (u >> 1) * 4;
            const bf16x4 lo = *(const bf16x4*)&t[d][k0];
            const bf16x4 hi = *(const bf16x4*)&t[d][k0 + 16];
            *(bf16x8*)(vb + m * 16) = __builtin_shufflevector(lo, hi, 0,1,2,3,4,5,6,7);
        }
    }
}

__global__ void mpack(const int* __restrict__ m, unsigned long long* __restrict__ mb) {
    const int i = blockIdx.x * 256 + threadIdx.x;
    const unsigned long long b = __ballot(m[i] != 0);
    if ((threadIdx.x & 63) == 0) mb[i >> 6] = b;
}

// ---------------- main kernel ----------------
// Block = 256 thr = 4 waves over 64 q-rows: wave (qp = w&1 -> which 32 q, kh = w>>1 ->
// which 32-key half). Staging is now a pure 16KB image memcpy via global_load_lds x4/wave
// (no VALU shuffles, no LDS-write instructions, linear = conflict-free). PV + row-sum run
// as 16x16x32 (the permuted V image delivers both 16-key groups per b128 read; the merged
// A operand pa8 = concat(group0, group1) uses the same key permutation, so the contraction
// is unchanged). One barrier per iteration; compiler's pre-barrier vmcnt(0) drains the
// prefetch, which has the whole compute phase to cover its latency.

__global__ __launch_bounds__(256, 4) void attn9(
    const float* __restrict__ q, const char* __restrict__ img,
    const unsigned long long* __restrict__ mb, float* __restrict__ out)
{
    const int qt = blockIdx.x;   // 0..31 (64 q rows per block)
    const int bh = blockIdx.y;   // 0..31
    const int tid = threadIdx.x, wave = tid >> 6, lane = tid & 63;
    const int g = lane >> 4, ln = lane & 15;
    const int qp = wave & 1, kh = wave >> 1;

    __shared__ __align__(16) char smem[33280];
    // main loop: buffer b at smem + b*16384 (K 8KB, then V 8KB), linear in lane order
    float* Ep = (float*)smem;                // epilogue overlay: [2][64][64] f32
    float* Os = (float*)(smem + 32768);      // row sums [2][64]

    const int qw = qt * 64 + qp * 32;

    // ---- Q B-frags (log2-scaled): lane n=ln holds Q[qw+qs*16+ln][kc*32+g*8+j]
    bf16x8 qf[2][2];
#pragma unroll
    for (int qs = 0; qs < 2; ++qs) {
        const float* qpt = q + ((size_t)bh * T_SEQ + qw + qs * 16 + ln) * D_HEAD + g * 8;
#pragma unroll
        for (int kc = 0; kc < 2; ++kc) {
            const float4 f0 = *(const float4*)(qpt + kc * 32);
            const float4 f1 = *(const float4*)(qpt + kc * 32 + 4);
            qf[qs][kc][0]=(__bf16)(f0.x*SCALE_LOG2); qf[qs][kc][1]=(__bf16)(f0.y*SCALE_LOG2);
            qf[qs][kc][2]=(__bf16)(f0.z*SCALE_LOG2); qf[qs][kc][3]=(__bf16)(f0.w*SCALE_LOG2);
            qf[qs][kc][4]=(__bf16)(f1.x*SCALE_LOG2); qf[qs][kc][5]=(__bf16)(f1.y*SCALE_LOG2);
            qf[qs][kc][6]=(__bf16)(f1.z*SCALE_LOG2); qf[qs][kc][7]=(__bf16)(f1.w*SCALE_LOG2);
        }
    }

    f32x4 o[2][4];
#pragma unroll
    for (int qs = 0; qs < 2; ++qs)
#pragma unroll
        for (int mt = 0; mt < 4; ++mt) o[qs][mt] = (f32x4){0.f, 0.f, 0.f, 0.f};
    f32x4 osum[2] = { (f32x4){0.f,0.f,0.f,0.f}, (f32x4){0.f,0.f,0.f,0.f} };
    const bf16x8 ones8 = { (__bf16)1.0f, (__bf16)1.0f, (__bf16)1.0f, (__bf16)1.0f,
                           (__bf16)1.0f, (__bf16)1.0f, (__bf16)1.0f, (__bf16)1.0f };

    const char* ibase = img + (size_t)bh * (NT_TILES * (size_t)IMG_BYTES);
    const unsigned long long* mrow0 = mb + (size_t)(qw + ln) * 32;
    const unsigned long long* mrow1 = mb + (size_t)(qw + 16 + ln) * 32;

    // prologue: tile 0 -> buf0
    {
        const char* src = ibase + wave * 4096 + lane * 16;
        char* dst = smem + wave * 4096;
#pragma unroll
        for (int i = 0; i < 4; ++i) gload16(src + i * 1024, dst + i * 1024, lane);
    }
    unsigned long long mw0 = mrow0[0], mw1 = mrow1[0];
    __syncthreads();

    for (int kt = 0; kt < NT_TILES; ++kt) {
        const int b = kt & 1;
        unsigned long long mn0 = 0, mn1 = 0;
        if (kt < NT_TILES - 1) {
            const char* src = ibase + (size_t)(kt + 1) * IMG_BYTES + wave * 4096 + lane * 16;
            char* dst = smem + (b ^ 1) * 16384 + wave * 4096;
#pragma unroll
            for (int i = 0; i < 4; ++i) gload16(src + i * 1024, dst + i * 1024, lane);
            mn0 = mrow0[kt + 1]; mn1 = mrow1[kt + 1];
        }

        const char* KB = smem + b * 16384;
        const char* VB = KB + 8192;

        // pre-inverted keep-bit words for this wave's 32-key half, pre-shifted by g*4
        const unsigned nbs0 = (~(unsigned)(mw0 >> (kh << 5))) >> (g * 4);
        const unsigned nbs1 = (~(unsigned)(mw1 >> (kh << 5))) >> (g * 4);

        // ---- S^T = K.Q^T; exp2 + mask -> merged P frags (key perm: j<4 -> grp0, j>=4 -> grp1)
        bf16x8 pa8[2];
#pragma unroll
        for (int ntl = 0; ntl < 2; ++ntl) {
            const int row = (2 * kh + ntl) * 16 + ln;
            const int rb = row * 128 + ((g ^ (ln & 7)) << 4);
            const bf16x8 a0 = *(const bf16x8*)(KB + rb);
            const bf16x8 a1 = *(const bf16x8*)(KB + (rb ^ 64));
#pragma unroll
            for (int qs = 0; qs < 2; ++qs) {
                f32x4 c = (f32x4){0.f, 0.f, 0.f, 0.f};
                c = mfma32(a0, qf[qs][0], c);
                c = mfma32(a1, qf[qs][1], c);
                const unsigned nbs = qs ? nbs1 : nbs0;
#pragma unroll
                for (int r = 0; r < 4; ++r) {
                    const float e = fast_exp2(c[r]);
                    const int keep = (int)(nbs << (31 - (ntl * 16 + r))) >> 31;
                    const float p = __builtin_bit_cast(float,
                        __builtin_bit_cast(unsigned, e) & (unsigned)keep);
                    pa8[qs][ntl * 4 + r] = (__bf16)p;
                }
            }
        }

        // ---- row-sum + PV, all 16x16x32 (B-frag vv covers both key groups per b128 read)
#pragma unroll
        for (int qs = 0; qs < 2; ++qs) osum[qs] = mfma32(pa8[qs], ones8, osum[qs]);
#pragma unroll
        for (int mt = 0; mt < 4; ++mt) {
            const bf16x8 vv = *(const bf16x8*)(VB + (mt * 16 + ln) * 128
                                + ((((g << 1) | kh) ^ (ln & 7)) << 4));
#pragma unroll
            for (int qs = 0; qs < 2; ++qs)
                o[qs][mt] = mfma32(pa8[qs], vv, o[qs][mt]);
        }

        __syncthreads();   // drains prefetch vmcnt; all waves done reading buf b
        mw0 = mn0; mw1 = mn1;
    }

    // ---- epilogue: combine kh halves through LDS (K/V buffers are dead now)
#pragma unroll
    for (int qs = 0; qs < 2; ++qs) {
#pragma unroll
        for (int mt = 0; mt < 4; ++mt)
#pragma unroll
            for (int r = 0; r < 4; ++r)
                Ep[(size_t)kh * 4096 + (qp * 32 + qs * 16 + g * 4 + r) * 64 + mt * 16 + ln] = o[qs][mt][r];
        if (ln == 0) {
#pragma unroll
            for (int r = 0; r < 4; ++r)
                Os[kh * 64 + qp * 32 + qs * 16 + g * 4 + r] = osum[qs][r];
        }
    }
    __syncthreads();
    // cooperative, coalesced output: 64 rows x 64 d fp32
#pragma unroll
    for (int p = 0; p < 4; ++p) {
        const int idx = p * 256 + tid;
        const int row = idx >> 4, c4 = (idx & 15) * 4;
        const float l = Os[row] + Os[64 + row];
        const float inv = (l > 0.f) ? (1.f / l) : 0.f;
        const float4 a  = *(const float4*)(Ep + row * 64 + c4);
        const float4 b4 = *(const float4*)(Ep + 4096 + row * 64 + c4);
        const float4 st = { (a.x + b4.x) * inv, (a.y + b4.y) * inv,
                            (a.z + b4.z) * inv, (a.w + b4.w) * inv };
        *(float4*)(out + ((size_t)bh * T_SEQ + qt * 64 + row) * D_HEAD + c4) = st;
    }
}

extern "C" void kernel_launch(void* const* d_in, const int* in_sizes, int n_in,
                              void* d_out, int out_size, void* d_ws, size_t ws_size,
                              hipStream_t stream) {
    const float* q    = (const float*)d_in[0];
    const float* k    = (const float*)d_in[1];
    const float* v    = (const float*)d_in[2];
    const int*   mask = (const int*)d_in[3];
    float*       out  = (float*)d_out;

    char* img = (char*)d_ws + WS_IMG;
    unsigned long long* mbw = (unsigned long long*)((char*)d_ws + WS_MB);

    prep_kv<<<dim3(NT_TILES, BH_N), 256, 0, stream>>>(k, v, img);
    mpack<<<(T_SEQ * T_SEQ) / 256, 256, 0, stream>>>(mask, mbw);
    attn9<<<dim3(NT_TILES, BH_N), 256, 0, stream>>>(q, img, mbw, out);
}